// Round 12
// baseline (98.244 us; speedup 1.0000x reference)
//
#include <hip/hip_runtime.h>
#include <hip/hip_bf16.h>

// Problem constants (fixed-shape problem)
#define KNB    32
#define DEMB   128
#define HIDN   100
#define OUTU   20
#define HHEADS 5
#define OUTW   228   // H*OUT + D = 100 + 128

#define HROWS  64    // emb rows per sa_hproj block

typedef __attribute__((ext_vector_type(4))) float f32x4;
typedef __attribute__((ext_vector_type(8))) short bf16x8;

__device__ __forceinline__ unsigned short f2bf(float f) {
    union { float f; unsigned u; } v; v.f = f;
    unsigned r = (v.u + 0x7fffu + ((v.u >> 16) & 1u)) >> 16;
    return (unsigned short)r;
}
__device__ __forceinline__ unsigned pkbf(float lo, float hi) {
    unsigned r;
    asm("v_cvt_pk_bf16_f32 %0, %1, %2" : "=v"(r) : "v"(lo), "v"(hi));
    return r;
}
__device__ __forceinline__ bf16x8 cvt8(float4 a, float4 b) {
    union { unsigned u[4]; bf16x8 v; } t;
    t.u[0] = pkbf(a.x, a.y); t.u[1] = pkbf(a.z, a.w);
    t.u[2] = pkbf(b.x, b.y); t.u[3] = pkbf(b.z, b.w);
    return t.v;
}

// ---------------- prep: frag-major W1 halves + W2 ----------------
__global__ void sa_prep(const float* __restrict__ W1, const float* __restrict__ W2,
                        unsigned short* __restrict__ W1fN, unsigned short* __restrict__ W1fM,
                        unsigned short* __restrict__ W2f) {
    int idx = blockIdx.x * 256 + threadIdx.x;          // 32768 total
    if (idx < 14336) {
        int e = idx & 7, lane = (idx >> 3) & 63, ks = (idx >> 9) & 3, jt = idx >> 11;
        int j = jt * 16 + (lane & 15);
        int d = ks * 32 + (lane >> 4) * 8 + e;
        W1fN[idx] = (j < HIDN) ? f2bf(W1[d * HIDN + j]) : (unsigned short)0;
    } else if (idx < 28672) {
        int i2 = idx - 14336;
        int e = i2 & 7, lane = (i2 >> 3) & 63, ks = (i2 >> 9) & 3, jt = i2 >> 11;
        int j = jt * 16 + (lane & 15);
        int d = ks * 32 + (lane >> 4) * 8 + e;
        W1fM[i2] = (j < HIDN) ? f2bf(W1[(128 + d) * HIDN + j]) : (unsigned short)0;
    } else {
        int i2 = idx - 28672;                          // < 4096
        int e = i2 & 7, lane = (i2 >> 3) & 63, ot = (i2 >> 9) & 1, ks = i2 >> 10;
        int o = ot * 16 + (lane & 15);
        int jj = ks * 32 + (lane >> 4) * 8 + e;
        W2f[i2] = (o < OUTU && jj < HIDN) ? f2bf(W2[jj * OUTU + o]) : (unsigned short)0;
    }
}

// ---------------- hproj: streaming GEMM via coalesced LDS staging (unchanged, works) ----------------
__global__ __launch_bounds__(256, 5)
void sa_hproj(const float* __restrict__ emb, const unsigned short* __restrict__ W1fN,
              unsigned short* __restrict__ hproj, int ntot) {
    __shared__ char xs[HROWS * 512];     // 32 KB
    const int tid = threadIdx.x, lane = tid & 63, wid = tid >> 6;
    const int l15 = lane & 15, h4 = lane >> 4;
    const size_t rbase = (size_t)blockIdx.x * HROWS;

#pragma unroll
    for (int i = 0; i < 8; ++i) {
        int off = tid * 16 + i * 4096;
        int row = off >> 9, col = off & 511;
        size_t gr = rbase + row; if (gr >= (size_t)ntot) gr = (size_t)ntot - 1;
        float4 v = *(const float4*)((const char*)emb + gr * 512 + col);
        *(float4*)(xs + row * 512 + (col ^ ((row & 7) << 4))) = v;
    }
    __syncthreads();

    const int mrow = wid * 16;
    const bf16x8* wv = (const bf16x8*)W1fN;
    f32x4 acc[7] = {};
#pragma unroll
    for (int ks = 0; ks < 4; ++ks) {
        const int r = mrow + l15;
        const int sw = (l15 & 7) << 4;
        const int cb = ks * 128 + h4 * 32;
        float4 e0 = *(const float4*)(xs + r * 512 + ((cb)      ^ sw));
        float4 e1 = *(const float4*)(xs + r * 512 + ((cb + 16) ^ sw));
        bf16x8 b = cvt8(e0, e1);
#pragma unroll
        for (int jt = 0; jt < 7; ++jt)
            acc[jt] = __builtin_amdgcn_mfma_f32_16x16x32_bf16(wv[(jt * 4 + ks) * 64 + lane], b, acc[jt], 0, 0, 0);
    }
#pragma unroll
    for (int jt = 0; jt < 8; ++jt) {
        int j0 = jt * 16 + h4 * 4;
        size_t r = rbase + mrow + l15;
        if (r < (size_t)ntot) {
            uint2 v;
            if (jt < 7) v = make_uint2(pkbf(acc[jt][0], acc[jt][1]), pkbf(acc[jt][2], acc[jt][3]));
            else        v = make_uint2(0u, 0u);
            *(uint2*)((char*)hproj + r * 256 + j0 * 2) = v;
        }
    }
}

// ---------------- nproj: node-half projection + b1, NOW bf16 out (4 lines/row) ----------------
__global__ __launch_bounds__(256, 2)
void sa_nproj(const float* __restrict__ emb, const int* __restrict__ node_idx,
              const float* __restrict__ b1, const unsigned short* __restrict__ W1fM,
              unsigned short* __restrict__ nproj, int nn) {
    const int tid = threadIdx.x, lane = tid & 63, wid = tid >> 6;
    const int l15 = lane & 15, h4 = lane >> 4;
    const int n0 = blockIdx.x * 128 + wid * 32 + l15;
    const int n1 = n0 + 16;
    const int n0c = n0 < nn ? n0 : nn - 1;
    const int n1c = n1 < nn ? n1 : nn - 1;
    const float* p0 = emb + (size_t)node_idx[n0c] * DEMB + h4 * 8;
    const float* p1 = emb + (size_t)node_idx[n1c] * DEMB + h4 * 8;
    const bf16x8* wv = (const bf16x8*)W1fM;

    f32x4 acc[7][2] = {};
#pragma unroll
    for (int ks = 0; ks < 4; ++ks) {
        bf16x8 b0 = cvt8(*(const float4*)(p0 + ks * 32), *(const float4*)(p0 + ks * 32 + 4));
        bf16x8 b1v = cvt8(*(const float4*)(p1 + ks * 32), *(const float4*)(p1 + ks * 32 + 4));
#pragma unroll
        for (int jt = 0; jt < 7; ++jt) {
            bf16x8 a = wv[(jt * 4 + ks) * 64 + lane];
            acc[jt][0] = __builtin_amdgcn_mfma_f32_16x16x32_bf16(a, b0, acc[jt][0], 0, 0, 0);
            acc[jt][1] = __builtin_amdgcn_mfma_f32_16x16x32_bf16(a, b1v, acc[jt][1], 0, 0, 0);
        }
    }
#pragma unroll
    for (int jt = 0; jt < 8; ++jt) {
        int j0 = jt * 16 + h4 * 4;
        float4 bv;
        if (jt < 7 && j0 + 3 < HIDN) bv = *(const float4*)(b1 + j0);
        else bv = make_float4(0.f, 0.f, 0.f, 0.f);
#pragma unroll
        for (int mt = 0; mt < 2; ++mt) {
            int n = mt ? n1 : n0;
            if (n < nn) {
                uint2 v;
                if (jt < 7) {
                    f32x4 a = acc[jt][mt];
                    v = make_uint2(pkbf(a[0] + bv.x, a[1] + bv.y), pkbf(a[2] + bv.z, a[3] + bv.w));
                } else v = make_uint2(0u, 0u);
                *(uint2*)((char*)nproj + (size_t)n * 256 + j0 * 2) = v;
            }
        }
    }
}

// hid A-frag: relu(bf16(hproj) + bf16(nproj)) -> packed bf16x8
__device__ __forceinline__ unsigned hidword(unsigned h, unsigned n) {
    union { unsigned u; float f; } hl, hh, nl, nh;
    hl.u = h << 16; hh.u = h & 0xffff0000u;
    nl.u = n << 16; nh.u = n & 0xffff0000u;
    return pkbf(fmaxf(hl.f + nl.f, 0.f), fmaxf(hh.f + nh.f, 0.f));
}
__device__ __forceinline__ bf16x8 mkhid2(uint4 hp, uint4 np) {
    union { unsigned u[4]; bf16x8 v; } t;
    t.u[0] = hidword(hp.x, np.x);
    t.u[1] = hidword(hp.y, np.y);
    t.u[2] = hidword(hp.z, np.z);
    t.u[3] = hidword(hp.w, np.w);
    return t.v;
}

// ---------------- main: 2 nodes/wave pipelined; B's gathers hide under A's epilogue ----------------
__global__ __launch_bounds__(256, 4)
void sa_main(const float* __restrict__ emb,
             const int* __restrict__ node_idx,
             const int* __restrict__ neigh_idx,
             const float* __restrict__ b2,
             const float* __restrict__ Wa,
             const float* __restrict__ ba,
             const unsigned short* __restrict__ hproj,
             const unsigned short* __restrict__ nproj,
             const unsigned short* __restrict__ W2f,
             float* __restrict__ out, int nnodes) {
    __shared__ char smem[4 * 3520];
    const int tid = threadIdx.x, lane = tid & 63, wid = tid >> 6;
    const int l15 = lane & 15, h4 = lane >> 4;

    char* wbase = smem + wid * 3520;
    float* tT_s = (float*)wbase;              // 20*36*4 = 2880 B
    float* pf_s = (float*)(wbase + 2880);     // 160*4   = 640 B

    const int node0 = blockIdx.x * 8 + wid * 2;    // 2500 x 4 x 2 = 20000 exact
    const int node1 = node0 + 1;
    const int n0c = node0 < nnodes ? node0 : nnodes - 1;
    const int n1c = node1 < nnodes ? node1 : nnodes - 1;

    // W2 fragments resident (coalesced, L1-hot)
    bf16x8 w2r[4][2];
#pragma unroll
    for (int ks = 0; ks < 4; ++ks)
#pragma unroll
        for (int ot = 0; ot < 2; ++ot)
            w2r[ks][ot] = ((const bf16x8*)W2f)[(ks * 2 + ot) * 64 + lane];

    // ---- issue node A gathers ----
    uint4 gA0[4], gA1[4], npA[4];
    float4 ncpA;
    {
        const int* nip = neigh_idx + (size_t)n0c * KNB;
        const int m0 = nip[l15], m1 = nip[16 + l15];
        const int nid = node_idx[n0c];
        const char* hp0 = (const char*)hproj + (size_t)m0 * 256 + h4 * 16;
        const char* hp1 = (const char*)hproj + (size_t)m1 * 256 + h4 * 16;
        const char* np  = (const char*)nproj + (size_t)n0c * 256 + h4 * 16;
#pragma unroll
        for (int ks = 0; ks < 4; ++ks) {
            gA0[ks] = *(const uint4*)(hp0 + ks * 64);
            gA1[ks] = *(const uint4*)(hp1 + ks * 64);
            npA[ks] = *(const uint4*)(np + ks * 64);
        }
        if (lane < 32) ncpA = ((const float4*)(emb + (size_t)nid * DEMB))[lane];
    }
    __builtin_amdgcn_sched_barrier(0);

    // ---- GEMM2 node A ----
    f32x4 accA[2][2] = {};
#pragma unroll
    for (int ks = 0; ks < 4; ++ks) {
        bf16x8 a0 = mkhid2(gA0[ks], npA[ks]);
        bf16x8 a1 = mkhid2(gA1[ks], npA[ks]);
        accA[0][0] = __builtin_amdgcn_mfma_f32_16x16x32_bf16(a0, w2r[ks][0], accA[0][0], 0, 0, 0);
        accA[0][1] = __builtin_amdgcn_mfma_f32_16x16x32_bf16(a0, w2r[ks][1], accA[0][1], 0, 0, 0);
        accA[1][0] = __builtin_amdgcn_mfma_f32_16x16x32_bf16(a1, w2r[ks][0], accA[1][0], 0, 0, 0);
        accA[1][1] = __builtin_amdgcn_mfma_f32_16x16x32_bf16(a1, w2r[ks][1], accA[1][1], 0, 0, 0);
    }
    __builtin_amdgcn_sched_barrier(0);

    // ---- issue node B gathers (fly under A's epilogue) ----
    uint4 gB0[4], gB1[4], npB[4];
    float4 ncpB;
    {
        const int* nip = neigh_idx + (size_t)n1c * KNB;
        const int m0 = nip[l15], m1 = nip[16 + l15];
        const int nid = node_idx[n1c];
        const char* hp0 = (const char*)hproj + (size_t)m0 * 256 + h4 * 16;
        const char* hp1 = (const char*)hproj + (size_t)m1 * 256 + h4 * 16;
        const char* np  = (const char*)nproj + (size_t)n1c * 256 + h4 * 16;
#pragma unroll
        for (int ks = 0; ks < 4; ++ks) {
            gB0[ks] = *(const uint4*)(hp0 + ks * 64);
            gB1[ks] = *(const uint4*)(hp1 + ks * 64);
            npB[ks] = *(const uint4*)(np + ks * 64);
        }
        if (lane < 32) ncpB = ((const float4*)(emb + (size_t)nid * DEMB))[lane];
    }
    __builtin_amdgcn_sched_barrier(0);

    // ================= epilogue helper (macro-style lambda) =================
    auto epilogue = [&](int node, f32x4 acc[2][2], float4 ncp) {
        if (lane < 32 && node < nnodes)
            ((float4*)(out + (size_t)node * OUTW + HHEADS * OUTU))[lane] = ncp;
        // t = relu(D2 + b2) -> tT[o][m]
#pragma unroll
        for (int ot = 0; ot < 2; ++ot) {
            int o = ot * 16 + l15;
            if (o < OUTU) {
                float b2v = b2[o];
#pragma unroll
                for (int mt = 0; mt < 2; ++mt) {
                    int mm0 = mt * 16 + h4 * 4;
                    f32x4 a = acc[mt][ot];
                    *(float4*)&tT_s[o * 36 + mm0] =
                        make_float4(fmaxf(a[0] + b2v, 0.f), fmaxf(a[1] + b2v, 0.f),
                                    fmaxf(a[2] + b2v, 0.f), fmaxf(a[3] + b2v, 0.f));
                }
            }
        }
        // attention + softmax over heads
        {
            int mm = lane & 31;
            float tv[20];
#pragma unroll
            for (int o = 0; o < OUTU; ++o) tv[o] = tT_s[o * 36 + mm];
            float att[5];
#pragma unroll
            for (int h = 0; h < HHEADS; ++h) {
                float s = ba[h];
#pragma unroll
                for (int o = 0; o < OUTU; ++o) s += tv[o] * Wa[o * HHEADS + h];
                att[h] = fmaxf(s, 0.f);
            }
            float mx = att[0];
#pragma unroll
            for (int h = 1; h < HHEADS; ++h) mx = fmaxf(mx, att[h]);
            float e[5], sum = 0.f;
#pragma unroll
            for (int h = 0; h < HHEADS; ++h) { e[h] = __expf(att[h] - mx); sum += e[h]; }
            float inv = 1.f / sum;
            if (lane < 32) {
#pragma unroll
                for (int h = 0; h < HHEADS; ++h) pf_s[mm * HHEADS + h] = e[h] * inv;
            }
        }
        // aggregate: out[n, h*20+o] = sum_k pf[h*32+k] * t[k][o]
#pragma unroll
        for (int pass = 0; pass < 2; ++pass) {
            int idx = pass * 64 + lane;
            if (idx < HHEADS * OUTU && node < nnodes) {
                int h = idx / OUTU, o = idx % OUTU;
                float s = 0.f;
#pragma unroll
                for (int kk = 0; kk < 8; ++kk) {
                    float4 p4 = *(const float4*)&pf_s[h * 32 + kk * 4];
                    float4 t4 = *(const float4*)&tT_s[o * 36 + kk * 4];
                    s += p4.x * t4.x + p4.y * t4.y + p4.z * t4.z + p4.w * t4.w;
                }
                out[(size_t)node * OUTW + idx] = s;
            }
        }
    };

    // ---- epilogue A (B's gathers in flight) ----
    epilogue(node0, accA, ncpA);
    __builtin_amdgcn_sched_barrier(0);

    // ---- GEMM2 node B ----
    f32x4 accB[2][2] = {};
#pragma unroll
    for (int ks = 0; ks < 4; ++ks) {
        bf16x8 a0 = mkhid2(gB0[ks], npB[ks]);
        bf16x8 a1 = mkhid2(gB1[ks], npB[ks]);
        accB[0][0] = __builtin_amdgcn_mfma_f32_16x16x32_bf16(a0, w2r[ks][0], accB[0][0], 0, 0, 0);
        accB[0][1] = __builtin_amdgcn_mfma_f32_16x16x32_bf16(a0, w2r[ks][1], accB[0][1], 0, 0, 0);
        accB[1][0] = __builtin_amdgcn_mfma_f32_16x16x32_bf16(a1, w2r[ks][0], accB[1][0], 0, 0, 0);
        accB[1][1] = __builtin_amdgcn_mfma_f32_16x16x32_bf16(a1, w2r[ks][1], accB[1][1], 0, 0, 0);
    }

    // ---- epilogue B ----
    epilogue(node1, accB, ncpB);
}

extern "C" void kernel_launch(void* const* d_in, const int* in_sizes, int n_in,
                              void* d_out, int out_size, void* d_ws, size_t ws_size,
                              hipStream_t stream) {
    const float* emb      = (const float*)d_in[0];
    const int*   node_idx = (const int*)d_in[1];
    const int*   neigh_idx= (const int*)d_in[2];
    const float* W1       = (const float*)d_in[3];
    const float* b1       = (const float*)d_in[4];
    const float* W2       = (const float*)d_in[5];
    const float* b2       = (const float*)d_in[6];
    const float* Wa       = (const float*)d_in[7];
    const float* ba       = (const float*)d_in[8];
    float* out = (float*)d_out;

    int ntot = in_sizes[0] / DEMB;                          // 200000
    int n    = in_sizes[1];                                 // 20000

    // ws layout
    unsigned short* W1fN = (unsigned short*)d_ws;                        // 28672 B
    unsigned short* W1fM = W1fN + 14336;                                 // 28672 B
    unsigned short* W2f  = W1fM + 14336;                                 //  8192 B
    unsigned short* hproj = (unsigned short*)((char*)d_ws + 65536);      // ntot*128*2
    unsigned short* nproj = (unsigned short*)((char*)d_ws + 65536 + (size_t)ntot * 256);  // n*128*2

    sa_prep<<<128, 256, 0, stream>>>(W1, W2, W1fN, W1fM, W2f);
    sa_hproj<<<(ntot + HROWS - 1) / HROWS, 256, 0, stream>>>(emb, W1fN, hproj, ntot);
    sa_nproj<<<(n + 127) / 128, 256, 0, stream>>>(emb, node_idx, b1, W1fM, nproj, n);
    sa_main<<<(n + 7) / 8, 256, 0, stream>>>(
        emb, node_idx, neigh_idx, b2, Wa, ba, hproj, nproj, W2f, out, n);
}

// Round 13
// 89.302 us; speedup vs baseline: 1.1001x; 1.1001x over previous
//
#include <hip/hip_runtime.h>
#include <hip/hip_bf16.h>

// Problem constants (fixed-shape problem)
#define KNB    32
#define DEMB   128
#define HIDN   100
#define OUTU   20
#define HHEADS 5
#define OUTW   228   // H*OUT + D = 100 + 128

#define HROWS  64    // emb rows per sa_hproj block
#define NPROJ_BLKS 157   // nproj part: 157*128 >= 20000
#define PACK_BLKS  625   // pack part: 625*32 = 20000

typedef __attribute__((ext_vector_type(4))) float f32x4;
typedef __attribute__((ext_vector_type(8))) short bf16x8;

__device__ __forceinline__ unsigned short f2bf(float f) {
    union { float f; unsigned u; } v; v.f = f;
    unsigned r = (v.u + 0x7fffu + ((v.u >> 16) & 1u)) >> 16;
    return (unsigned short)r;
}
__device__ __forceinline__ unsigned pkbf(float lo, float hi) {
    unsigned r;
    asm("v_cvt_pk_bf16_f32 %0, %1, %2" : "=v"(r) : "v"(lo), "v"(hi));
    return r;
}
__device__ __forceinline__ bf16x8 cvt8(float4 a, float4 b) {
    union { unsigned u[4]; bf16x8 v; } t;
    t.u[0] = pkbf(a.x, a.y); t.u[1] = pkbf(a.z, a.w);
    t.u[2] = pkbf(b.x, b.y); t.u[3] = pkbf(b.z, b.w);
    return t.v;
}

// ---------------- prep: frag-major W1 halves + W2 ----------------
__global__ void sa_prep(const float* __restrict__ W1, const float* __restrict__ W2,
                        unsigned short* __restrict__ W1fN, unsigned short* __restrict__ W1fM,
                        unsigned short* __restrict__ W2f) {
    int idx = blockIdx.x * 256 + threadIdx.x;          // 32768 total
    if (idx < 14336) {
        int e = idx & 7, lane = (idx >> 3) & 63, ks = (idx >> 9) & 3, jt = idx >> 11;
        int j = jt * 16 + (lane & 15);
        int d = ks * 32 + (lane >> 4) * 8 + e;
        W1fN[idx] = (j < HIDN) ? f2bf(W1[d * HIDN + j]) : (unsigned short)0;
    } else if (idx < 28672) {
        int i2 = idx - 14336;
        int e = i2 & 7, lane = (i2 >> 3) & 63, ks = (i2 >> 9) & 3, jt = i2 >> 11;
        int j = jt * 16 + (lane & 15);
        int d = ks * 32 + (lane >> 4) * 8 + e;
        W1fM[i2] = (j < HIDN) ? f2bf(W1[(128 + d) * HIDN + j]) : (unsigned short)0;
    } else {
        int i2 = idx - 28672;                          // < 4096
        int e = i2 & 7, lane = (i2 >> 3) & 63, ot = (i2 >> 9) & 1, ks = i2 >> 10;
        int o = ot * 16 + (lane & 15);
        int jj = ks * 32 + (lane >> 4) * 8 + e;
        W2f[i2] = (o < OUTU && jj < HIDN) ? f2bf(W2[jj * OUTU + o]) : (unsigned short)0;
    }
}

// ---------------- hproj: streaming GEMM via coalesced LDS staging (unchanged, works) ----------------
__global__ __launch_bounds__(256, 5)
void sa_hproj(const float* __restrict__ emb, const unsigned short* __restrict__ W1fN,
              unsigned short* __restrict__ hproj, int ntot) {
    __shared__ char xs[HROWS * 512];     // 32 KB
    const int tid = threadIdx.x, lane = tid & 63, wid = tid >> 6;
    const int l15 = lane & 15, h4 = lane >> 4;
    const size_t rbase = (size_t)blockIdx.x * HROWS;

#pragma unroll
    for (int i = 0; i < 8; ++i) {
        int off = tid * 16 + i * 4096;
        int row = off >> 9, col = off & 511;
        size_t gr = rbase + row; if (gr >= (size_t)ntot) gr = (size_t)ntot - 1;
        float4 v = *(const float4*)((const char*)emb + gr * 512 + col);
        *(float4*)(xs + row * 512 + (col ^ ((row & 7) << 4))) = v;
    }
    __syncthreads();

    const int mrow = wid * 16;
    const bf16x8* wv = (const bf16x8*)W1fN;
    f32x4 acc[7] = {};
#pragma unroll
    for (int ks = 0; ks < 4; ++ks) {
        const int r = mrow + l15;
        const int sw = (l15 & 7) << 4;
        const int cb = ks * 128 + h4 * 32;
        float4 e0 = *(const float4*)(xs + r * 512 + ((cb)      ^ sw));
        float4 e1 = *(const float4*)(xs + r * 512 + ((cb + 16) ^ sw));
        bf16x8 b = cvt8(e0, e1);
#pragma unroll
        for (int jt = 0; jt < 7; ++jt)
            acc[jt] = __builtin_amdgcn_mfma_f32_16x16x32_bf16(wv[(jt * 4 + ks) * 64 + lane], b, acc[jt], 0, 0, 0);
    }
#pragma unroll
    for (int jt = 0; jt < 8; ++jt) {
        int j0 = jt * 16 + h4 * 4;
        size_t r = rbase + mrow + l15;
        if (r < (size_t)ntot) {
            uint2 v;
            if (jt < 7) v = make_uint2(pkbf(acc[jt][0], acc[jt][1]), pkbf(acc[jt][2], acc[jt][3]));
            else        v = make_uint2(0u, 0u);
            *(uint2*)((char*)hproj + r * 256 + j0 * 2) = v;
        }
    }
}

// ---------------- nproj (bf16 out) + node-row pack, fused in one dispatch ----------------
__global__ __launch_bounds__(256, 2)
void sa_nproj(const float* __restrict__ emb, const int* __restrict__ node_idx,
              const float* __restrict__ b1, const unsigned short* __restrict__ W1fM,
              unsigned short* __restrict__ nproj, float* __restrict__ out, int nn) {
    const int tid = threadIdx.x, lane = tid & 63, wid = tid >> 6;

    if (blockIdx.x >= NPROJ_BLKS) {
        // ---- pack: out[n, 100..227] = emb[node_idx[n]] (coalesced both sides) ----
        int base = (blockIdx.x - NPROJ_BLKS) * 32 + wid * 8;
        int l31 = lane & 31, sel = lane >> 5;
#pragma unroll
        for (int it = 0; it < 4; ++it) {
            int node = base + it * 2 + sel;
            if (node < nn) {
                int nid = node_idx[node];
                float4 v = ((const float4*)(emb + (size_t)nid * DEMB))[l31];
                ((float4*)(out + (size_t)node * OUTW + HHEADS * OUTU))[l31] = v;
            }
        }
        return;
    }

    const int l15 = lane & 15, h4 = lane >> 4;
    const int n0 = blockIdx.x * 128 + wid * 32 + l15;
    const int n1 = n0 + 16;
    const int n0c = n0 < nn ? n0 : nn - 1;
    const int n1c = n1 < nn ? n1 : nn - 1;
    const float* p0 = emb + (size_t)node_idx[n0c] * DEMB + h4 * 8;
    const float* p1 = emb + (size_t)node_idx[n1c] * DEMB + h4 * 8;
    const bf16x8* wv = (const bf16x8*)W1fM;

    f32x4 acc[7][2] = {};
#pragma unroll
    for (int ks = 0; ks < 4; ++ks) {
        bf16x8 b0 = cvt8(*(const float4*)(p0 + ks * 32), *(const float4*)(p0 + ks * 32 + 4));
        bf16x8 b1v = cvt8(*(const float4*)(p1 + ks * 32), *(const float4*)(p1 + ks * 32 + 4));
#pragma unroll
        for (int jt = 0; jt < 7; ++jt) {
            bf16x8 a = wv[(jt * 4 + ks) * 64 + lane];
            acc[jt][0] = __builtin_amdgcn_mfma_f32_16x16x32_bf16(a, b0, acc[jt][0], 0, 0, 0);
            acc[jt][1] = __builtin_amdgcn_mfma_f32_16x16x32_bf16(a, b1v, acc[jt][1], 0, 0, 0);
        }
    }
#pragma unroll
    for (int jt = 0; jt < 8; ++jt) {
        int j0 = jt * 16 + h4 * 4;
        float4 bv;
        if (jt < 7 && j0 + 3 < HIDN) bv = *(const float4*)(b1 + j0);
        else bv = make_float4(0.f, 0.f, 0.f, 0.f);
#pragma unroll
        for (int mt = 0; mt < 2; ++mt) {
            int n = mt ? n1 : n0;
            if (n < nn) {
                uint2 v;
                if (jt < 7) {
                    f32x4 a = acc[jt][mt];
                    v = make_uint2(pkbf(a[0] + bv.x, a[1] + bv.y), pkbf(a[2] + bv.z, a[3] + bv.w));
                } else v = make_uint2(0u, 0u);
                *(uint2*)((char*)nproj + (size_t)n * 256 + j0 * 2) = v;
            }
        }
    }
}

// hid A-frag: relu(bf16(hproj) + bf16(nproj)) -> packed bf16x8
__device__ __forceinline__ unsigned hidword(unsigned h, unsigned n) {
    union { unsigned u; float f; } hl, hh, nl, nh;
    hl.u = h << 16; hh.u = h & 0xffff0000u;
    nl.u = n << 16; nh.u = n & 0xffff0000u;
    return pkbf(fmaxf(hl.f + nl.f, 0.f), fmaxf(hh.f + nh.f, 0.f));
}
__device__ __forceinline__ bf16x8 mkhid2(uint4 hp, uint4 np) {
    union { unsigned u[4]; bf16x8 v; } t;
    t.u[0] = hidword(hp.x, np.x);
    t.u[1] = hidword(hp.y, np.y);
    t.u[2] = hidword(hp.z, np.z);
    t.u[3] = hidword(hp.w, np.w);
    return t.v;
}

// ---------------- main: 1 node/wave (R11-proven), bf16 nproj, no node-copy ----------------
__global__ __launch_bounds__(256, 4)
void sa_main(const int* __restrict__ neigh_idx,
             const float* __restrict__ b2,
             const float* __restrict__ Wa,
             const float* __restrict__ ba,
             const unsigned short* __restrict__ hproj,
             const unsigned short* __restrict__ nproj,
             const unsigned short* __restrict__ W2f,
             float* __restrict__ out, int nnodes) {
    __shared__ char smem[4 * 3520];
    const int tid = threadIdx.x, lane = tid & 63, wid = tid >> 6;
    const int l15 = lane & 15, h4 = lane >> 4;

    char* wbase = smem + wid * 3520;
    float* tT_s = (float*)wbase;              // 20*36*4 = 2880 B
    float* pf_s = (float*)(wbase + 2880);     // 160*4   = 640 B

    const int node = blockIdx.x * 4 + wid;    // 5000 x 4 = 20000 exact
    if (node >= nnodes) return;
    const int* nip = neigh_idx + (size_t)node * KNB;
    const int m0 = nip[l15], m1 = nip[16 + l15];

    // ---- issue all gathers ----
    const char* hp0 = (const char*)hproj + (size_t)m0 * 256 + h4 * 16;
    const char* hp1 = (const char*)hproj + (size_t)m1 * 256 + h4 * 16;
    const char* np  = (const char*)nproj + (size_t)node * 256 + h4 * 16;
    uint4 g0[4], g1[4], npv[4];
#pragma unroll
    for (int ks = 0; ks < 4; ++ks) {
        g0[ks]  = *(const uint4*)(hp0 + ks * 64);
        g1[ks]  = *(const uint4*)(hp1 + ks * 64);
        npv[ks] = *(const uint4*)(np + ks * 64);
    }

    // W2 fragments (coalesced, L1/L2-hot)
    bf16x8 w2r[4][2];
#pragma unroll
    for (int ks = 0; ks < 4; ++ks)
#pragma unroll
        for (int ot = 0; ot < 2; ++ot)
            w2r[ks][ot] = ((const bf16x8*)W2f)[(ks * 2 + ot) * 64 + lane];

    __builtin_amdgcn_sched_barrier(0);

    // ---- GEMM2: hid built in-register from hproj+nproj ----
    f32x4 acc[2][2] = {};
#pragma unroll
    for (int ks = 0; ks < 4; ++ks) {
        bf16x8 a0 = mkhid2(g0[ks], npv[ks]);
        bf16x8 a1 = mkhid2(g1[ks], npv[ks]);
        acc[0][0] = __builtin_amdgcn_mfma_f32_16x16x32_bf16(a0, w2r[ks][0], acc[0][0], 0, 0, 0);
        acc[0][1] = __builtin_amdgcn_mfma_f32_16x16x32_bf16(a0, w2r[ks][1], acc[0][1], 0, 0, 0);
        acc[1][0] = __builtin_amdgcn_mfma_f32_16x16x32_bf16(a1, w2r[ks][0], acc[1][0], 0, 0, 0);
        acc[1][1] = __builtin_amdgcn_mfma_f32_16x16x32_bf16(a1, w2r[ks][1], acc[1][1], 0, 0, 0);
    }

    // ---- t = relu(D2 + b2), store transposed tT[o][m] ----
#pragma unroll
    for (int ot = 0; ot < 2; ++ot) {
        int o = ot * 16 + l15;
        if (o < OUTU) {
            float b2v = b2[o];
#pragma unroll
            for (int mt = 0; mt < 2; ++mt) {
                int mm0 = mt * 16 + h4 * 4;
                f32x4 a = acc[mt][ot];
                *(float4*)&tT_s[o * 36 + mm0] =
                    make_float4(fmaxf(a[0] + b2v, 0.f), fmaxf(a[1] + b2v, 0.f),
                                fmaxf(a[2] + b2v, 0.f), fmaxf(a[3] + b2v, 0.f));
            }
        }
    }

    // ---- attention + softmax over heads ----
    {
        int mm = lane & 31;
        float tv[20];
#pragma unroll
        for (int o = 0; o < OUTU; ++o) tv[o] = tT_s[o * 36 + mm];
        float att[5];
#pragma unroll
        for (int h = 0; h < HHEADS; ++h) {
            float s = ba[h];
#pragma unroll
            for (int o = 0; o < OUTU; ++o) s += tv[o] * Wa[o * HHEADS + h];
            att[h] = fmaxf(s, 0.f);
        }
        float mx = att[0];
#pragma unroll
        for (int h = 1; h < HHEADS; ++h) mx = fmaxf(mx, att[h]);
        float e[5], sum = 0.f;
#pragma unroll
        for (int h = 0; h < HHEADS; ++h) { e[h] = __expf(att[h] - mx); sum += e[h]; }
        float inv = 1.f / sum;
        if (lane < 32) {
#pragma unroll
            for (int h = 0; h < HHEADS; ++h) pf_s[mm * HHEADS + h] = e[h] * inv;
        }
    }

    // ---- aggregate: out[n, h*20+o] = sum_k pf[h*32+k] * t[k][o]  (reshape-faithful) ----
#pragma unroll
    for (int pass = 0; pass < 2; ++pass) {
        int idx = pass * 64 + lane;
        if (idx < HHEADS * OUTU) {
            int h = idx / OUTU, o = idx % OUTU;
            float s = 0.f;
#pragma unroll
            for (int kk = 0; kk < 8; ++kk) {
                float4 p4 = *(const float4*)&pf_s[h * 32 + kk * 4];
                float4 t4 = *(const float4*)&tT_s[o * 36 + kk * 4];
                s += p4.x * t4.x + p4.y * t4.y + p4.z * t4.z + p4.w * t4.w;
            }
            out[(size_t)node * OUTW + idx] = s;
        }
    }
}

extern "C" void kernel_launch(void* const* d_in, const int* in_sizes, int n_in,
                              void* d_out, int out_size, void* d_ws, size_t ws_size,
                              hipStream_t stream) {
    const float* emb      = (const float*)d_in[0];
    const int*   node_idx = (const int*)d_in[1];
    const int*   neigh_idx= (const int*)d_in[2];
    const float* W1       = (const float*)d_in[3];
    const float* b1       = (const float*)d_in[4];
    const float* W2       = (const float*)d_in[5];
    const float* b2       = (const float*)d_in[6];
    const float* Wa       = (const float*)d_in[7];
    const float* ba       = (const float*)d_in[8];
    float* out = (float*)d_out;

    int ntot = in_sizes[0] / DEMB;                          // 200000
    int n    = in_sizes[1];                                 // 20000

    // ws layout
    unsigned short* W1fN = (unsigned short*)d_ws;                        // 28672 B
    unsigned short* W1fM = W1fN + 14336;                                 // 28672 B
    unsigned short* W2f  = W1fM + 14336;                                 //  8192 B
    unsigned short* hproj = (unsigned short*)((char*)d_ws + 65536);      // ntot*128*2
    unsigned short* nproj = (unsigned short*)((char*)d_ws + 65536 + (size_t)ntot * 256);  // n*128*2

    sa_prep<<<128, 256, 0, stream>>>(W1, W2, W1fN, W1fM, W2f);
    sa_hproj<<<(ntot + HROWS - 1) / HROWS, 256, 0, stream>>>(emb, W1fN, hproj, ntot);
    sa_nproj<<<NPROJ_BLKS + PACK_BLKS, 256, 0, stream>>>(emb, node_idx, b1, W1fM, nproj, out, n);
    sa_main<<<(n + 3) / 4, 256, 0, stream>>>(
        neigh_idx, b2, Wa, ba, hproj, nproj, W2f, out, n);
}

// Round 14
// 82.923 us; speedup vs baseline: 1.1848x; 1.0769x over previous
//
#include <hip/hip_runtime.h>
#include <hip/hip_bf16.h>

// Problem constants (fixed-shape problem)
#define KNB    32
#define DEMB   128
#define HIDN   100
#define OUTU   20
#define HHEADS 5
#define OUTW   228   // H*OUT + D = 100 + 128

#define HROWS  64    // emb rows per sa_hproj block
#define NPROJ_BLKS 157   // nproj part: 157*128 >= 20000
#define PACK_BLKS  625   // pack part: 625*32 = 20000

typedef __attribute__((ext_vector_type(4))) float f32x4;
typedef __attribute__((ext_vector_type(2))) float f32x2;
typedef __attribute__((ext_vector_type(8))) short bf16x8;

__device__ __forceinline__ unsigned short f2bf(float f) {
    union { float f; unsigned u; } v; v.f = f;
    unsigned r = (v.u + 0x7fffu + ((v.u >> 16) & 1u)) >> 16;
    return (unsigned short)r;
}
__device__ __forceinline__ unsigned pkbf(float lo, float hi) {
    unsigned r;
    asm("v_cvt_pk_bf16_f32 %0, %1, %2" : "=v"(r) : "v"(lo), "v"(hi));
    return r;
}
__device__ __forceinline__ bf16x8 cvt8(float4 a, float4 b) {
    union { unsigned u[4]; bf16x8 v; } t;
    t.u[0] = pkbf(a.x, a.y); t.u[1] = pkbf(a.z, a.w);
    t.u[2] = pkbf(b.x, b.y); t.u[3] = pkbf(b.z, b.w);
    return t.v;
}

// ---------------- prep: frag-major W1 halves + W2 ----------------
__global__ void sa_prep(const float* __restrict__ W1, const float* __restrict__ W2,
                        unsigned short* __restrict__ W1fN, unsigned short* __restrict__ W1fM,
                        unsigned short* __restrict__ W2f) {
    int idx = blockIdx.x * 256 + threadIdx.x;          // 32768 total
    if (idx < 14336) {
        int e = idx & 7, lane = (idx >> 3) & 63, ks = (idx >> 9) & 3, jt = idx >> 11;
        int j = jt * 16 + (lane & 15);
        int d = ks * 32 + (lane >> 4) * 8 + e;
        W1fN[idx] = (j < HIDN) ? f2bf(W1[d * HIDN + j]) : (unsigned short)0;
    } else if (idx < 28672) {
        int i2 = idx - 14336;
        int e = i2 & 7, lane = (i2 >> 3) & 63, ks = (i2 >> 9) & 3, jt = i2 >> 11;
        int j = jt * 16 + (lane & 15);
        int d = ks * 32 + (lane >> 4) * 8 + e;
        W1fM[i2] = (j < HIDN) ? f2bf(W1[(128 + d) * HIDN + j]) : (unsigned short)0;
    } else {
        int i2 = idx - 28672;                          // < 4096
        int e = i2 & 7, lane = (i2 >> 3) & 63, ot = (i2 >> 9) & 1, ks = i2 >> 10;
        int o = ot * 16 + (lane & 15);
        int jj = ks * 32 + (lane >> 4) * 8 + e;
        W2f[i2] = (o < OUTU && jj < HIDN) ? f2bf(W2[jj * OUTU + o]) : (unsigned short)0;
    }
}

// ---------------- hproj: streaming GEMM, NOW fp8-e4m3 output (row = 128 B = 2 lines) ----------------
__global__ __launch_bounds__(256, 5)
void sa_hproj(const float* __restrict__ emb, const unsigned short* __restrict__ W1fN,
              unsigned char* __restrict__ hproj, int ntot) {
    __shared__ char xs[HROWS * 512];     // 32 KB
    const int tid = threadIdx.x, lane = tid & 63, wid = tid >> 6;
    const int l15 = lane & 15, h4 = lane >> 4;
    const size_t rbase = (size_t)blockIdx.x * HROWS;

#pragma unroll
    for (int i = 0; i < 8; ++i) {
        int off = tid * 16 + i * 4096;
        int row = off >> 9, col = off & 511;
        size_t gr = rbase + row; if (gr >= (size_t)ntot) gr = (size_t)ntot - 1;
        float4 v = *(const float4*)((const char*)emb + gr * 512 + col);
        *(float4*)(xs + row * 512 + (col ^ ((row & 7) << 4))) = v;
    }
    __syncthreads();

    const int mrow = wid * 16;
    const bf16x8* wv = (const bf16x8*)W1fN;
    f32x4 acc[7] = {};
#pragma unroll
    for (int ks = 0; ks < 4; ++ks) {
        const int r = mrow + l15;
        const int sw = (l15 & 7) << 4;
        const int cb = ks * 128 + h4 * 32;
        float4 e0 = *(const float4*)(xs + r * 512 + ((cb)      ^ sw));
        float4 e1 = *(const float4*)(xs + r * 512 + ((cb + 16) ^ sw));
        bf16x8 b = cvt8(e0, e1);
#pragma unroll
        for (int jt = 0; jt < 7; ++jt)
            acc[jt] = __builtin_amdgcn_mfma_f32_16x16x32_bf16(wv[(jt * 4 + ks) * 64 + lane], b, acc[jt], 0, 0, 0);
    }
    // store fp8 rows: 4 cols -> 4 bytes per (jt, r); cols [100,128) zero
#pragma unroll
    for (int jt = 0; jt < 8; ++jt) {
        int j0 = jt * 16 + h4 * 4;
        size_t r = rbase + mrow + l15;
        if (r < (size_t)ntot) {
            unsigned u = 0;
            if (jt < 7) {
                u = __builtin_amdgcn_cvt_pk_fp8_f32(acc[jt][0], acc[jt][1], 0, false);
                u = __builtin_amdgcn_cvt_pk_fp8_f32(acc[jt][2], acc[jt][3], u, true);
            }
            *(unsigned*)(hproj + r * 128 + j0) = u;
        }
    }
}

// ---------------- nproj (bf16 out) + node-row pack, fused in one dispatch ----------------
__global__ __launch_bounds__(256, 2)
void sa_nproj(const float* __restrict__ emb, const int* __restrict__ node_idx,
              const float* __restrict__ b1, const unsigned short* __restrict__ W1fM,
              unsigned short* __restrict__ nproj, float* __restrict__ out, int nn) {
    const int tid = threadIdx.x, lane = tid & 63, wid = tid >> 6;

    if (blockIdx.x >= NPROJ_BLKS) {
        // ---- pack: out[n, 100..227] = emb[node_idx[n]] (coalesced both sides) ----
        int base = (blockIdx.x - NPROJ_BLKS) * 32 + wid * 8;
        int l31 = lane & 31, sel = lane >> 5;
#pragma unroll
        for (int it = 0; it < 4; ++it) {
            int node = base + it * 2 + sel;
            if (node < nn) {
                int nid = node_idx[node];
                float4 v = ((const float4*)(emb + (size_t)nid * DEMB))[l31];
                ((float4*)(out + (size_t)node * OUTW + HHEADS * OUTU))[l31] = v;
            }
        }
        return;
    }

    const int l15 = lane & 15, h4 = lane >> 4;
    const int n0 = blockIdx.x * 128 + wid * 32 + l15;
    const int n1 = n0 + 16;
    const int n0c = n0 < nn ? n0 : nn - 1;
    const int n1c = n1 < nn ? n1 : nn - 1;
    const float* p0 = emb + (size_t)node_idx[n0c] * DEMB + h4 * 8;
    const float* p1 = emb + (size_t)node_idx[n1c] * DEMB + h4 * 8;
    const bf16x8* wv = (const bf16x8*)W1fM;

    f32x4 acc[7][2] = {};
#pragma unroll
    for (int ks = 0; ks < 4; ++ks) {
        bf16x8 b0 = cvt8(*(const float4*)(p0 + ks * 32), *(const float4*)(p0 + ks * 32 + 4));
        bf16x8 b1v = cvt8(*(const float4*)(p1 + ks * 32), *(const float4*)(p1 + ks * 32 + 4));
#pragma unroll
        for (int jt = 0; jt < 7; ++jt) {
            bf16x8 a = wv[(jt * 4 + ks) * 64 + lane];
            acc[jt][0] = __builtin_amdgcn_mfma_f32_16x16x32_bf16(a, b0, acc[jt][0], 0, 0, 0);
            acc[jt][1] = __builtin_amdgcn_mfma_f32_16x16x32_bf16(a, b1v, acc[jt][1], 0, 0, 0);
        }
    }
#pragma unroll
    for (int jt = 0; jt < 8; ++jt) {
        int j0 = jt * 16 + h4 * 4;
        float4 bv;
        if (jt < 7 && j0 + 3 < HIDN) bv = *(const float4*)(b1 + j0);
        else bv = make_float4(0.f, 0.f, 0.f, 0.f);
#pragma unroll
        for (int mt = 0; mt < 2; ++mt) {
            int n = mt ? n1 : n0;
            if (n < nn) {
                uint2 v;
                if (jt < 7) {
                    f32x4 a = acc[jt][mt];
                    v = make_uint2(pkbf(a[0] + bv.x, a[1] + bv.y), pkbf(a[2] + bv.z, a[3] + bv.w));
                } else v = make_uint2(0u, 0u);
                *(uint2*)((char*)nproj + (size_t)n * 256 + j0 * 2) = v;
            }
        }
    }
}

// hid A-frag: relu(fp8(hproj) + bf16(nproj)) -> packed bf16x8
__device__ __forceinline__ unsigned hidw(f32x2 h, unsigned npw) {
    union { unsigned u; float f; } nl, nh;
    nl.u = npw << 16; nh.u = npw & 0xffff0000u;
    return pkbf(fmaxf(h.x + nl.f, 0.f), fmaxf(h.y + nh.f, 0.f));
}
__device__ __forceinline__ bf16x8 mkhid8(uint2 g, uint4 np) {
    union { unsigned u[4]; bf16x8 v; } t;
    t.u[0] = hidw(__builtin_amdgcn_cvt_pk_f32_fp8(g.x, false), np.x);
    t.u[1] = hidw(__builtin_amdgcn_cvt_pk_f32_fp8(g.x, true),  np.y);
    t.u[2] = hidw(__builtin_amdgcn_cvt_pk_f32_fp8(g.y, false), np.z);
    t.u[3] = hidw(__builtin_amdgcn_cvt_pk_f32_fp8(g.y, true),  np.w);
    return t.v;
}

// ---------------- main: 1 node/wave, fp8 hproj gathers (2 lines/row) ----------------
__global__ __launch_bounds__(256, 4)
void sa_main(const int* __restrict__ neigh_idx,
             const float* __restrict__ b2,
             const float* __restrict__ Wa,
             const float* __restrict__ ba,
             const unsigned char* __restrict__ hproj,
             const unsigned short* __restrict__ nproj,
             const unsigned short* __restrict__ W2f,
             float* __restrict__ out, int nnodes) {
    __shared__ char smem[4 * 3520];
    const int tid = threadIdx.x, lane = tid & 63, wid = tid >> 6;
    const int l15 = lane & 15, h4 = lane >> 4;

    char* wbase = smem + wid * 3520;
    float* tT_s = (float*)wbase;              // 20*36*4 = 2880 B
    float* pf_s = (float*)(wbase + 2880);     // 160*4   = 640 B

    const int node = blockIdx.x * 4 + wid;    // 5000 x 4 = 20000 exact
    if (node >= nnodes) return;
    const int* nip = neigh_idx + (size_t)node * KNB;
    const int m0 = nip[l15], m1 = nip[16 + l15];

    // ---- issue all gathers (fp8 rows: 8 B/lane/frag) ----
    const unsigned char* hp0 = hproj + (size_t)m0 * 128 + h4 * 8;
    const unsigned char* hp1 = hproj + (size_t)m1 * 128 + h4 * 8;
    const char* np  = (const char*)nproj + (size_t)node * 256 + h4 * 16;
    uint2 g0[4], g1[4]; uint4 npv[4];
#pragma unroll
    for (int ks = 0; ks < 4; ++ks) {
        g0[ks]  = *(const uint2*)(hp0 + ks * 32);
        g1[ks]  = *(const uint2*)(hp1 + ks * 32);
        npv[ks] = *(const uint4*)(np + ks * 64);
    }

    // W2 fragments (coalesced, L1/L2-hot)
    bf16x8 w2r[4][2];
#pragma unroll
    for (int ks = 0; ks < 4; ++ks)
#pragma unroll
        for (int ot = 0; ot < 2; ++ot)
            w2r[ks][ot] = ((const bf16x8*)W2f)[(ks * 2 + ot) * 64 + lane];

    __builtin_amdgcn_sched_barrier(0);

    // ---- GEMM2: hid built in-register from fp8 hproj + bf16 nproj ----
    f32x4 acc[2][2] = {};
#pragma unroll
    for (int ks = 0; ks < 4; ++ks) {
        bf16x8 a0 = mkhid8(g0[ks], npv[ks]);
        bf16x8 a1 = mkhid8(g1[ks], npv[ks]);
        acc[0][0] = __builtin_amdgcn_mfma_f32_16x16x32_bf16(a0, w2r[ks][0], acc[0][0], 0, 0, 0);
        acc[0][1] = __builtin_amdgcn_mfma_f32_16x16x32_bf16(a0, w2r[ks][1], acc[0][1], 0, 0, 0);
        acc[1][0] = __builtin_amdgcn_mfma_f32_16x16x32_bf16(a1, w2r[ks][0], acc[1][0], 0, 0, 0);
        acc[1][1] = __builtin_amdgcn_mfma_f32_16x16x32_bf16(a1, w2r[ks][1], acc[1][1], 0, 0, 0);
    }

    // ---- t = relu(D2 + b2), store transposed tT[o][m] ----
#pragma unroll
    for (int ot = 0; ot < 2; ++ot) {
        int o = ot * 16 + l15;
        if (o < OUTU) {
            float b2v = b2[o];
#pragma unroll
            for (int mt = 0; mt < 2; ++mt) {
                int mm0 = mt * 16 + h4 * 4;
                f32x4 a = acc[mt][ot];
                *(float4*)&tT_s[o * 36 + mm0] =
                    make_float4(fmaxf(a[0] + b2v, 0.f), fmaxf(a[1] + b2v, 0.f),
                                fmaxf(a[2] + b2v, 0.f), fmaxf(a[3] + b2v, 0.f));
            }
        }
    }

    // ---- attention + softmax over heads ----
    {
        int mm = lane & 31;
        float tv[20];
#pragma unroll
        for (int o = 0; o < OUTU; ++o) tv[o] = tT_s[o * 36 + mm];
        float att[5];
#pragma unroll
        for (int h = 0; h < HHEADS; ++h) {
            float s = ba[h];
#pragma unroll
            for (int o = 0; o < OUTU; ++o) s += tv[o] * Wa[o * HHEADS + h];
            att[h] = fmaxf(s, 0.f);
        }
        float mx = att[0];
#pragma unroll
        for (int h = 1; h < HHEADS; ++h) mx = fmaxf(mx, att[h]);
        float e[5], sum = 0.f;
#pragma unroll
        for (int h = 0; h < HHEADS; ++h) { e[h] = __expf(att[h] - mx); sum += e[h]; }
        float inv = 1.f / sum;
        if (lane < 32) {
#pragma unroll
            for (int h = 0; h < HHEADS; ++h) pf_s[mm * HHEADS + h] = e[h] * inv;
        }
    }

    // ---- aggregate: out[n, h*20+o] = sum_k pf[h*32+k] * t[k][o]  (reshape-faithful) ----
#pragma unroll
    for (int pass = 0; pass < 2; ++pass) {
        int idx = pass * 64 + lane;
        if (idx < HHEADS * OUTU) {
            int h = idx / OUTU, o = idx % OUTU;
            float s = 0.f;
#pragma unroll
            for (int kk = 0; kk < 8; ++kk) {
                float4 p4 = *(const float4*)&pf_s[h * 32 + kk * 4];
                float4 t4 = *(const float4*)&tT_s[o * 36 + kk * 4];
                s += p4.x * t4.x + p4.y * t4.y + p4.z * t4.z + p4.w * t4.w;
            }
            out[(size_t)node * OUTW + idx] = s;
        }
    }
}

extern "C" void kernel_launch(void* const* d_in, const int* in_sizes, int n_in,
                              void* d_out, int out_size, void* d_ws, size_t ws_size,
                              hipStream_t stream) {
    const float* emb      = (const float*)d_in[0];
    const int*   node_idx = (const int*)d_in[1];
    const int*   neigh_idx= (const int*)d_in[2];
    const float* W1       = (const float*)d_in[3];
    const float* b1       = (const float*)d_in[4];
    const float* W2       = (const float*)d_in[5];
    const float* b2       = (const float*)d_in[6];
    const float* Wa       = (const float*)d_in[7];
    const float* ba       = (const float*)d_in[8];
    float* out = (float*)d_out;

    int ntot = in_sizes[0] / DEMB;                          // 200000
    int n    = in_sizes[1];                                 // 20000

    // ws layout
    unsigned short* W1fN = (unsigned short*)d_ws;                        // 28672 B
    unsigned short* W1fM = W1fN + 14336;                                 // 28672 B
    unsigned short* W2f  = W1fM + 14336;                                 //  8192 B
    unsigned char*  hproj = (unsigned char*)d_ws + 65536;                // ntot*128 (fp8)
    unsigned short* nproj = (unsigned short*)(hproj + (size_t)ntot * 128);  // n*128*2 (bf16)

    sa_prep<<<128, 256, 0, stream>>>(W1, W2, W1fN, W1fM, W2f);
    sa_hproj<<<(ntot + HROWS - 1) / HROWS, 256, 0, stream>>>(emb, W1fN, hproj, ntot);
    sa_nproj<<<NPROJ_BLKS + PACK_BLKS, 256, 0, stream>>>(emb, node_idx, b1, W1fM, nproj, out, n);
    sa_main<<<(n + 3) / 4, 256, 0, stream>>>(
        neigh_idx, b2, Wa, ba, hproj, nproj, W2f, out, n);
}

// Round 15
// 80.459 us; speedup vs baseline: 1.2210x; 1.0306x over previous
//
#include <hip/hip_runtime.h>
#include <hip/hip_bf16.h>

// Problem constants (fixed-shape problem)
#define KNB    32
#define DEMB   128
#define HIDN   100
#define OUTU   20
#define HHEADS 5
#define OUTW   228   // H*OUT + D = 100 + 128

#define HROWS  64        // emb rows per hproj tile
#define NPROJ_BLKS 157   // nproj part: 157*128 >= 20000
#define PACK_BLKS  625   // pack part: 625*32 = 20000
#define HPROJ_BLKS 3125  // 200000/64

typedef __attribute__((ext_vector_type(4))) float f32x4;
typedef __attribute__((ext_vector_type(2))) float f32x2;
typedef __attribute__((ext_vector_type(8))) short bf16x8;

__device__ __forceinline__ unsigned short f2bf(float f) {
    union { float f; unsigned u; } v; v.f = f;
    unsigned r = (v.u + 0x7fffu + ((v.u >> 16) & 1u)) >> 16;
    return (unsigned short)r;
}
__device__ __forceinline__ unsigned pkbf(float lo, float hi) {
    unsigned r;
    asm("v_cvt_pk_bf16_f32 %0, %1, %2" : "=v"(r) : "v"(lo), "v"(hi));
    return r;
}
__device__ __forceinline__ bf16x8 cvt8(float4 a, float4 b) {
    union { unsigned u[4]; bf16x8 v; } t;
    t.u[0] = pkbf(a.x, a.y); t.u[1] = pkbf(a.z, a.w);
    t.u[2] = pkbf(b.x, b.y); t.u[3] = pkbf(b.z, b.w);
    return t.v;
}

// ---------------- prep: frag-major W1 halves + W2 ----------------
__global__ void sa_prep(const float* __restrict__ W1, const float* __restrict__ W2,
                        unsigned short* __restrict__ W1fN, unsigned short* __restrict__ W1fM,
                        unsigned short* __restrict__ W2f) {
    int idx = blockIdx.x * 256 + threadIdx.x;          // 32768 total
    if (idx < 14336) {
        int e = idx & 7, lane = (idx >> 3) & 63, ks = (idx >> 9) & 3, jt = idx >> 11;
        int j = jt * 16 + (lane & 15);
        int d = ks * 32 + (lane >> 4) * 8 + e;
        W1fN[idx] = (j < HIDN) ? f2bf(W1[d * HIDN + j]) : (unsigned short)0;
    } else if (idx < 28672) {
        int i2 = idx - 14336;
        int e = i2 & 7, lane = (i2 >> 3) & 63, ks = (i2 >> 9) & 3, jt = i2 >> 11;
        int j = jt * 16 + (lane & 15);
        int d = ks * 32 + (lane >> 4) * 8 + e;
        W1fM[i2] = (j < HIDN) ? f2bf(W1[(128 + d) * HIDN + j]) : (unsigned short)0;
    } else {
        int i2 = idx - 28672;                          // < 4096
        int e = i2 & 7, lane = (i2 >> 3) & 63, ot = (i2 >> 9) & 1, ks = i2 >> 10;
        int o = ot * 16 + (lane & 15);
        int jj = ks * 32 + (lane >> 4) * 8 + e;
        W2f[i2] = (o < OUTU && jj < HIDN) ? f2bf(W2[jj * OUTU + o]) : (unsigned short)0;
    }
}

// ---------------- mid: nproj (bf16) + node-pack + fp8 hproj, ONE dispatch ----------------
// Blocks [0,157): nproj. [157,782): pack. [782,3907): hproj tiles.
// nproj/pack first so their latency-bound gathers overlap the hproj stream.
__global__ __launch_bounds__(256, 4)
void sa_mid(const float* __restrict__ emb, const int* __restrict__ node_idx,
            const float* __restrict__ b1,
            const unsigned short* __restrict__ W1fN, const unsigned short* __restrict__ W1fM,
            unsigned char* __restrict__ hproj, unsigned short* __restrict__ nproj,
            float* __restrict__ out, int ntot, int nn) {
    __shared__ char xs[HROWS * 512];     // 32 KB (used by hproj blocks only)
    const int tid = threadIdx.x, lane = tid & 63, wid = tid >> 6;
    const int l15 = lane & 15, h4 = lane >> 4;

    if (blockIdx.x < NPROJ_BLKS) {
        // ---- nproj: node-half projection + b1, bf16 out ----
        const int n0 = blockIdx.x * 128 + wid * 32 + l15;
        const int n1 = n0 + 16;
        const int n0c = n0 < nn ? n0 : nn - 1;
        const int n1c = n1 < nn ? n1 : nn - 1;
        const float* p0 = emb + (size_t)node_idx[n0c] * DEMB + h4 * 8;
        const float* p1 = emb + (size_t)node_idx[n1c] * DEMB + h4 * 8;
        const bf16x8* wv = (const bf16x8*)W1fM;

        f32x4 acc[7][2] = {};
#pragma unroll
        for (int ks = 0; ks < 4; ++ks) {
            bf16x8 b0 = cvt8(*(const float4*)(p0 + ks * 32), *(const float4*)(p0 + ks * 32 + 4));
            bf16x8 b1v = cvt8(*(const float4*)(p1 + ks * 32), *(const float4*)(p1 + ks * 32 + 4));
#pragma unroll
            for (int jt = 0; jt < 7; ++jt) {
                bf16x8 a = wv[(jt * 4 + ks) * 64 + lane];
                acc[jt][0] = __builtin_amdgcn_mfma_f32_16x16x32_bf16(a, b0, acc[jt][0], 0, 0, 0);
                acc[jt][1] = __builtin_amdgcn_mfma_f32_16x16x32_bf16(a, b1v, acc[jt][1], 0, 0, 0);
            }
        }
#pragma unroll
        for (int jt = 0; jt < 8; ++jt) {
            int j0 = jt * 16 + h4 * 4;
            float4 bv;
            if (jt < 7 && j0 + 3 < HIDN) bv = *(const float4*)(b1 + j0);
            else bv = make_float4(0.f, 0.f, 0.f, 0.f);
#pragma unroll
            for (int mt = 0; mt < 2; ++mt) {
                int n = mt ? n1 : n0;
                if (n < nn) {
                    uint2 v;
                    if (jt < 7) {
                        f32x4 a = acc[jt][mt];
                        v = make_uint2(pkbf(a[0] + bv.x, a[1] + bv.y), pkbf(a[2] + bv.z, a[3] + bv.w));
                    } else v = make_uint2(0u, 0u);
                    *(uint2*)((char*)nproj + (size_t)n * 256 + j0 * 2) = v;
                }
            }
        }
        return;
    }

    if (blockIdx.x < NPROJ_BLKS + PACK_BLKS) {
        // ---- pack: out[n, 100..227] = emb[node_idx[n]] ----
        int base = (blockIdx.x - NPROJ_BLKS) * 32 + wid * 8;
        int l31 = lane & 31, sel = lane >> 5;
#pragma unroll
        for (int it = 0; it < 4; ++it) {
            int node = base + it * 2 + sel;
            if (node < nn) {
                int nid = node_idx[node];
                float4 v = ((const float4*)(emb + (size_t)nid * DEMB))[l31];
                ((float4*)(out + (size_t)node * OUTW + HHEADS * OUTU))[l31] = v;
            }
        }
        return;
    }

    // ---- hproj tile: coalesced LDS staging + fp8 output ----
    const size_t rbase = (size_t)(blockIdx.x - NPROJ_BLKS - PACK_BLKS) * HROWS;
#pragma unroll
    for (int i = 0; i < 8; ++i) {
        int off = tid * 16 + i * 4096;
        int row = off >> 9, col = off & 511;
        size_t gr = rbase + row; if (gr >= (size_t)ntot) gr = (size_t)ntot - 1;
        float4 v = *(const float4*)((const char*)emb + gr * 512 + col);
        *(float4*)(xs + row * 512 + (col ^ ((row & 7) << 4))) = v;
    }
    __syncthreads();

    const int mrow = wid * 16;
    const bf16x8* wv = (const bf16x8*)W1fN;
    f32x4 acc[7] = {};
#pragma unroll
    for (int ks = 0; ks < 4; ++ks) {
        const int r = mrow + l15;
        const int sw = (l15 & 7) << 4;
        const int cb = ks * 128 + h4 * 32;
        float4 e0 = *(const float4*)(xs + r * 512 + ((cb)      ^ sw));
        float4 e1 = *(const float4*)(xs + r * 512 + ((cb + 16) ^ sw));
        bf16x8 b = cvt8(e0, e1);
#pragma unroll
        for (int jt = 0; jt < 7; ++jt)
            acc[jt] = __builtin_amdgcn_mfma_f32_16x16x32_bf16(wv[(jt * 4 + ks) * 64 + lane], b, acc[jt], 0, 0, 0);
    }
#pragma unroll
    for (int jt = 0; jt < 8; ++jt) {
        int j0 = jt * 16 + h4 * 4;
        size_t r = rbase + mrow + l15;
        if (r < (size_t)ntot) {
            unsigned u = 0;
            if (jt < 7) {
                u = __builtin_amdgcn_cvt_pk_fp8_f32(acc[jt][0], acc[jt][1], 0, false);
                u = __builtin_amdgcn_cvt_pk_fp8_f32(acc[jt][2], acc[jt][3], u, true);
            }
            *(unsigned*)(hproj + r * 128 + j0) = u;
        }
    }
}

// hid A-frag: relu(fp8(hproj) + bf16(nproj)) -> packed bf16x8
__device__ __forceinline__ unsigned hidw(f32x2 h, unsigned npw) {
    union { unsigned u; float f; } nl, nh;
    nl.u = npw << 16; nh.u = npw & 0xffff0000u;
    return pkbf(fmaxf(h.x + nl.f, 0.f), fmaxf(h.y + nh.f, 0.f));
}
__device__ __forceinline__ bf16x8 mkhid8(uint2 g, uint4 np) {
    union { unsigned u[4]; bf16x8 v; } t;
    t.u[0] = hidw(__builtin_amdgcn_cvt_pk_f32_fp8(g.x, false), np.x);
    t.u[1] = hidw(__builtin_amdgcn_cvt_pk_f32_fp8(g.x, true),  np.y);
    t.u[2] = hidw(__builtin_amdgcn_cvt_pk_f32_fp8(g.y, false), np.z);
    t.u[3] = hidw(__builtin_amdgcn_cvt_pk_f32_fp8(g.y, true),  np.w);
    return t.v;
}

// ---------------- main: 1 node/wave, fp8 gathers; W2 in-loop (L1-hot) -> 24 waves/CU ----------------
__global__ __launch_bounds__(256, 6)
void sa_main(const int* __restrict__ neigh_idx,
             const float* __restrict__ b2,
             const float* __restrict__ Wa,
             const float* __restrict__ ba,
             const unsigned char* __restrict__ hproj,
             const unsigned short* __restrict__ nproj,
             const unsigned short* __restrict__ W2f,
             float* __restrict__ out, int nnodes) {
    __shared__ char smem[4 * 3520];
    const int tid = threadIdx.x, lane = tid & 63, wid = tid >> 6;
    const int l15 = lane & 15, h4 = lane >> 4;

    char* wbase = smem + wid * 3520;
    float* tT_s = (float*)wbase;              // 20*36*4 = 2880 B
    float* pf_s = (float*)(wbase + 2880);     // 160*4   = 640 B

    const int node = blockIdx.x * 4 + wid;    // 5000 x 4 = 20000 exact
    if (node >= nnodes) return;
    const int* nip = neigh_idx + (size_t)node * KNB;
    const int m0 = nip[l15], m1 = nip[16 + l15];

    // ---- issue all gathers (fp8 rows: 8 B/lane/frag) ----
    const unsigned char* hp0 = hproj + (size_t)m0 * 128 + h4 * 8;
    const unsigned char* hp1 = hproj + (size_t)m1 * 128 + h4 * 8;
    const char* np  = (const char*)nproj + (size_t)node * 256 + h4 * 16;
    uint2 g0[4], g1[4]; uint4 npv[4];
#pragma unroll
    for (int ks = 0; ks < 4; ++ks) {
        g0[ks]  = *(const uint2*)(hp0 + ks * 32);
        g1[ks]  = *(const uint2*)(hp1 + ks * 32);
        npv[ks] = *(const uint4*)(np + ks * 64);
    }
    __builtin_amdgcn_sched_barrier(0);

    // ---- GEMM2: hid in-register; W2 frags read in-loop (8 KB, L1-hot on every CU) ----
    f32x4 acc[2][2] = {};
#pragma unroll
    for (int ks = 0; ks < 4; ++ks) {
        bf16x8 w20 = ((const bf16x8*)W2f)[(ks * 2 + 0) * 64 + lane];
        bf16x8 w21 = ((const bf16x8*)W2f)[(ks * 2 + 1) * 64 + lane];
        bf16x8 a0 = mkhid8(g0[ks], npv[ks]);
        bf16x8 a1 = mkhid8(g1[ks], npv[ks]);
        acc[0][0] = __builtin_amdgcn_mfma_f32_16x16x32_bf16(a0, w20, acc[0][0], 0, 0, 0);
        acc[0][1] = __builtin_amdgcn_mfma_f32_16x16x32_bf16(a0, w21, acc[0][1], 0, 0, 0);
        acc[1][0] = __builtin_amdgcn_mfma_f32_16x16x32_bf16(a1, w20, acc[1][0], 0, 0, 0);
        acc[1][1] = __builtin_amdgcn_mfma_f32_16x16x32_bf16(a1, w21, acc[1][1], 0, 0, 0);
    }

    // ---- t = relu(D2 + b2), store transposed tT[o][m] ----
#pragma unroll
    for (int ot = 0; ot < 2; ++ot) {
        int o = ot * 16 + l15;
        if (o < OUTU) {
            float b2v = b2[o];
#pragma unroll
            for (int mt = 0; mt < 2; ++mt) {
                int mm0 = mt * 16 + h4 * 4;
                f32x4 a = acc[mt][ot];
                *(float4*)&tT_s[o * 36 + mm0] =
                    make_float4(fmaxf(a[0] + b2v, 0.f), fmaxf(a[1] + b2v, 0.f),
                                fmaxf(a[2] + b2v, 0.f), fmaxf(a[3] + b2v, 0.f));
            }
        }
    }

    // ---- attention + softmax over heads ----
    {
        int mm = lane & 31;
        float tv[20];
#pragma unroll
        for (int o = 0; o < OUTU; ++o) tv[o] = tT_s[o * 36 + mm];
        float att[5];
#pragma unroll
        for (int h = 0; h < HHEADS; ++h) {
            float s = ba[h];
#pragma unroll
            for (int o = 0; o < OUTU; ++o) s += tv[o] * Wa[o * HHEADS + h];
            att[h] = fmaxf(s, 0.f);
        }
        float mx = att[0];
#pragma unroll
        for (int h = 1; h < HHEADS; ++h) mx = fmaxf(mx, att[h]);
        float e[5], sum = 0.f;
#pragma unroll
        for (int h = 0; h < HHEADS; ++h) { e[h] = __expf(att[h] - mx); sum += e[h]; }
        float inv = 1.f / sum;
        if (lane < 32) {
#pragma unroll
            for (int h = 0; h < HHEADS; ++h) pf_s[mm * HHEADS + h] = e[h] * inv;
        }
    }

    // ---- aggregate: out[n, h*20+o] = sum_k pf[h*32+k] * t[k][o]  (reshape-faithful) ----
#pragma unroll
    for (int pass = 0; pass < 2; ++pass) {
        int idx = pass * 64 + lane;
        if (idx < HHEADS * OUTU) {
            int h = idx / OUTU, o = idx % OUTU;
            float s = 0.f;
#pragma unroll
            for (int kk = 0; kk < 8; ++kk) {
                float4 p4 = *(const float4*)&pf_s[h * 32 + kk * 4];
                float4 t4 = *(const float4*)&tT_s[o * 36 + kk * 4];
                s += p4.x * t4.x + p4.y * t4.y + p4.z * t4.z + p4.w * t4.w;
            }
            out[(size_t)node * OUTW + idx] = s;
        }
    }
}

extern "C" void kernel_launch(void* const* d_in, const int* in_sizes, int n_in,
                              void* d_out, int out_size, void* d_ws, size_t ws_size,
                              hipStream_t stream) {
    const float* emb      = (const float*)d_in[0];
    const int*   node_idx = (const int*)d_in[1];
    const int*   neigh_idx= (const int*)d_in[2];
    const float* W1       = (const float*)d_in[3];
    const float* b1       = (const float*)d_in[4];
    const float* W2       = (const float*)d_in[5];
    const float* b2       = (const float*)d_in[6];
    const float* Wa       = (const float*)d_in[7];
    const float* ba       = (const float*)d_in[8];
    float* out = (float*)d_out;

    int ntot = in_sizes[0] / DEMB;                          // 200000
    int n    = in_sizes[1];                                 // 20000

    // ws layout
    unsigned short* W1fN = (unsigned short*)d_ws;                        // 28672 B
    unsigned short* W1fM = W1fN + 14336;                                 // 28672 B
    unsigned short* W2f  = W1fM + 14336;                                 //  8192 B
    unsigned char*  hproj = (unsigned char*)d_ws + 65536;                // ntot*128 (fp8)
    unsigned short* nproj = (unsigned short*)(hproj + (size_t)ntot * 128);  // n*128*2 (bf16)

    sa_prep<<<128, 256, 0, stream>>>(W1, W2, W1fN, W1fM, W2f);
    sa_mid<<<NPROJ_BLKS + PACK_BLKS + HPROJ_BLKS, 256, 0, stream>>>(
        emb, node_idx, b1, W1fN, W1fM, hproj, nproj, out, ntot, n);
    sa_main<<<(n + 3) / 4, 256, 0, stream>>>(
        neigh_idx, b2, Wa, ba, hproj, nproj, W2f, out, n);
}